// Round 5
// baseline (143.177 us; speedup 1.0000x reference)
//
#include <hip/hip_runtime.h>
#include <math.h>

// Converse2D (USRNet closed-form prox), s=2, B=4, C=64, H=W=128, K=5.
// Per (b,c): 1 fwd 128x128 FFT, then two {K-mult + inv FFT} passes packing the
// 4 output polyphases. Fused radix-2 stage pairs (radix-4 traffic), float2 LDS.
//
// R1: precompute_K stores made output-contiguous (brev on input side).
// R2: launch_bounds(.,4) -> no effect (min-waves only raises the floor).
// R3: LDS-only barriers + K prefetch into regs; precompute LDS-free. Helped
//     precompute only; converse unchanged.
// R4: register-cap fix (bench infra failed; resubmitted R5 with conservative
//     attribute spelling). VGPR_Count pinned at exactly 64 across all rounds
//     even as live demand grew (sA/sB 32 + kr 32 + temps > 64): the allocator
//     targets the default 8-waves/EU occupancy (64-VGPR budget), ignoring that
//     132KB LDS caps the CU at 1 block = 4 waves/EU. Result: sA/sB/kr spilled
//     to scratch every round -> +50MiB phantom WRITE, +9MiB FETCH, and
//     scratch-reload latency on the lockstep barrier path (the ~60us gap
//     between component model and measured 85us).
//     Fix: __launch_bounds__(1024) + amdgpu_waves_per_eu(4,4) -- max=4 tells
//     the allocator occupancy cannot exceed 4 waves/EU, so budget = 512/4 =
//     128 VGPRs. Live state (~100) fits. precompute_K gets (2,8).

struct cx { float x, y; };
__device__ __forceinline__ cx cmul(cx a, cx b){ return cx{a.x*b.x - a.y*b.y, a.x*b.y + a.y*b.x}; }
__device__ __forceinline__ cx cadd(cx a, cx b){ return cx{a.x+b.x, a.y+b.y}; }
__device__ __forceinline__ cx csub(cx a, cx b){ return cx{a.x-b.x, a.y-b.y}; }
__device__ __forceinline__ cx cconj(cx a){ return cx{a.x, -a.y}; }
__device__ __forceinline__ cx cscale(cx a, float s){ return cx{a.x*s, a.y*s}; }

__device__ __forceinline__ float2 cmulf(float2 a, float2 b){
    return make_float2(a.x*b.x - a.y*b.y, a.x*b.y + a.y*b.x);
}
__device__ __forceinline__ float2 cmulcf(float2 a, float2 b){ // a * conj(b)
    return make_float2(a.x*b.x + a.y*b.y, a.y*b.x - a.x*b.y);
}
__device__ __forceinline__ float2 caddf(float2 a, float2 b){ return make_float2(a.x+b.x, a.y+b.y); }
__device__ __forceinline__ float2 csubf(float2 a, float2 b){ return make_float2(a.x-b.x, a.y-b.y); }

// LDS-only barrier: waits ds ops, leaves global loads/stores in flight.
__device__ __forceinline__ void barrier_lds(){
    __builtin_amdgcn_sched_barrier(0);
    asm volatile("s_waitcnt lgkmcnt(0)" ::: "memory");
    __builtin_amdgcn_s_barrier();
    __builtin_amdgcn_sched_barrier(0);
}

// ---------------- precompute_K: 1 point/thread, no LDS ----------------
__global__ __launch_bounds__(256) __attribute__((amdgpu_waves_per_eu(2, 8)))
void precompute_K(const float* __restrict__ weight, const float* __restrict__ lam_ptr,
                  float2* __restrict__ KA, float2* __restrict__ KB)
{
    const int tid = threadIdx.x;
    const int c   = blockIdx.x >> 6;                   // 64 blocks per channel
    const int p   = ((blockIdx.x & 63) << 8) + tid;    // 0..16383 (output index)
    const int qb = p >> 7, rb = p & 127;
    const int q = (int)(__brev((unsigned)qb) >> 25);   // brev on INPUT side
    const int r = (int)(__brev((unsigned)rb) >> 25);

    const float th = -6.28318530717958647692f * (1.0f/256.0f);
    float s1,c1, s2,c2, sq1,cq1, sq2,cq2;
    __sincosf(th * (float)r,       &s1,  &c1);
    __sincosf(th * (float)(2*r),   &s2,  &c2);
    __sincosf(th * (float)q,       &sq1, &cq1);
    __sincosf(th * (float)(2*q),   &sq2, &cq2);

    // er[t] = e^{-2*pi*i*r(t-2)/256}, t=0..4 (same values TAB lookups gave)
    cx er[5] = { cx{c2,-s2}, cx{c1,-s1}, cx{1.f,0.f}, cx{c1,s1}, cx{c2,s2} };
    cx eq[5] = { cx{cq2,-sq2}, cx{cq1,-sq1}, cx{1.f,0.f}, cx{cq1,sq1}, cx{cq2,sq2} };

    const float lam = lam_ptr[0];
    const float* wc = weight + c*25;                   // wave-uniform -> s_loads

    cx P0[5], P1[5];
    #pragma unroll
    for (int a = 0; a < 5; ++a) {
        cx p0{0.f,0.f}, p1{0.f,0.f};
        #pragma unroll
        for (int b = 0; b < 5; ++b) {
            cx t = cscale(er[b], wc[a*5 + b]);
            p0 = cadd(p0, t);
            p1 = (b & 1) ? csub(p1, t) : cadd(p1, t);
        }
        P0[a] = p0; P1[a] = p1;
    }
    cx F00{0.f,0.f}, F01{0.f,0.f}, F10{0.f,0.f}, F11{0.f,0.f};
    #pragma unroll
    for (int a = 0; a < 5; ++a) {
        cx t0 = cmul(eq[a], P0[a]);
        cx t1 = cmul(eq[a], P1[a]);
        F00 = cadd(F00, t0); F01 = cadd(F01, t1);
        if (a & 1) { F10 = csub(F10, t0); F11 = csub(F11, t1); }
        else       { F10 = cadd(F10, t0); F11 = cadd(F11, t1); }
    }
    const float cq = cq1, sq = sq1, cr = c1, sr = s1;
    cx Du[2] = { cx{1.f+cq,  sq}, cx{1.f-cq, -sq} };
    cx Dv[2] = { cx{1.f+cr,  sr}, cx{1.f-cr, -sr} };
    cx Fm[2][2] = { {F00, F01}, {F10, F11} };
    cx R[2][2];
    float invW = 0.f;
    cx M{0.f,0.f};
    #pragma unroll
    for (int i = 0; i < 2; ++i)
      #pragma unroll
      for (int k = 0; k < 2; ++k) {
        cx fb = Fm[i][k];
        cx Rik = cadd(cconj(fb), cscale(cmul(Du[i], Dv[k]), lam));
        R[i][k] = Rik;
        invW += 0.25f * (fb.x*fb.x + fb.y*fb.y);
        M = cadd(M, cscale(cmul(fb, Rik), 0.25f));
      }
    cx V = cscale(M, 1.0f / (invW + lam));
    float inv_lam = 1.0f / lam;
    cx G[2][2];
    #pragma unroll
    for (int i = 0; i < 2; ++i)
      #pragma unroll
      for (int k = 0; k < 2; ++k)
        G[i][k] = cscale(csub(R[i][k], cmul(cconj(Fm[i][k]), V)), inv_lam);

    cx G00 = G[0][0], G01 = G[0][1], G10 = G[1][0], G11 = G[1][1];
    cx Gh00 = cadd(cadd(G00,G01), cadd(G10,G11));
    cx Gh01 = cadd(csub(G00,G01), csub(G10,G11));
    cx Gh10 = csub(cadd(G00,G01), cadd(G10,G11));
    cx Gh11 = csub(csub(G00,G01), csub(G10,G11));
    cx phq = cx{cq, -sq};
    cx phr = cx{cr, -sr};
    cx H0 = Gh00;
    cx H1 = cmul(Gh01, phr);
    cx H2 = cmul(Gh10, phq);
    cx H3 = cmul(Gh11, cmul(phq, phr));

    const float scale = 1.0f / 65536.0f;   // ifft 1/(128*128) and 1/4 polyphase mean
    float2 kAv = make_float2((H0.x - H1.y)*scale, (H0.y + H1.x)*scale);
    float2 kBv = make_float2((H2.x - H3.y)*scale, (H2.y + H3.x)*scale);
    int o = (c << 14) + p;                 // contiguous across tid -> coalesced
    KA[o] = kAv;
    KB[o] = kBv;
}

#define ST2 129   // float2 stride: odd -> both row & col passes at bank-bandwidth minimum

template<int AXIS> __device__ __forceinline__ int laddr(int line, int i){
    return AXIS ? (i*ST2 + line) : (line*ST2 + i);
}

// Forward DIF, fused stages (S, S+1). S in {0,2,4}. 4096 quartets, 4/thread.
template<int AXIS, int S>
__device__ __forceinline__ void fwd_pair(float2* Sm, const float2* TW, int tid)
{
    const int h  = 64 >> S;
    const int hh = 32 >> S;
    #pragma unroll
    for (int it = 0; it < 4; ++it) {
        int qid  = it*1024 + tid;
        int line = qid & 127;
        int t    = qid >> 7;
        int blk  = t >> (5 - S);
        int j    = t & (hh - 1);
        int i0   = (blk << (7 - S)) + j;
        int a0 = laddr<AXIS>(line, i0);
        int a1 = laddr<AXIS>(line, i0 + hh);
        int a2 = laddr<AXIS>(line, i0 + h);
        int a3 = laddr<AXIS>(line, i0 + h + hh);
        float2 e0 = Sm[a0], e1 = Sm[a1], e2 = Sm[a2], e3 = Sm[a3];
        float2 w0 = TW[j << S], w1 = TW[(j << S) + 32], w2 = TW[j << (S + 1)];
        float2 u0 = caddf(e0, e2), d0 = cmulf(csubf(e0, e2), w0);
        float2 u1 = caddf(e1, e3), d1 = cmulf(csubf(e1, e3), w1);
        Sm[a0] = caddf(u0, u1);
        Sm[a1] = cmulf(csubf(u0, u1), w2);
        Sm[a2] = caddf(d0, d1);
        Sm[a3] = cmulf(csubf(d0, d1), w2);
    }
}

// Inverse DIT, fused stages (S, S+1). conj twiddles.
template<int AXIS, int S>
__device__ __forceinline__ void inv_pair(float2* Sm, const float2* TW, int tid)
{
    const int h = 1 << S;
    #pragma unroll
    for (int it = 0; it < 4; ++it) {
        int qid  = it*1024 + tid;
        int line = qid & 127;
        int t    = qid >> 7;
        int blk  = t >> S;
        int j    = t & (h - 1);
        int base = (blk << (S + 2)) + j;
        int a0 = laddr<AXIS>(line, base);
        int a1 = laddr<AXIS>(line, base + h);
        int a2 = laddr<AXIS>(line, base + 2*h);
        int a3 = laddr<AXIS>(line, base + 3*h);
        float2 e0 = Sm[a0], e1 = Sm[a1], e2 = Sm[a2], e3 = Sm[a3];
        float2 cw0 = TW[j << (6 - S)];
        float2 cw1 = TW[j << (5 - S)];
        float2 cw2 = TW[(j << (5 - S)) + 32];
        float2 t1 = cmulcf(e1, cw0);
        float2 A0 = caddf(e0, t1), A1 = csubf(e0, t1);
        float2 t2 = cmulcf(e3, cw0);
        float2 A2 = caddf(e2, t2), A3 = csubf(e2, t2);
        float2 u = cmulcf(A2, cw1);
        Sm[a0] = caddf(A0, u);
        Sm[a2] = csubf(A0, u);
        float2 v = cmulcf(A3, cw2);
        Sm[a1] = caddf(A1, v);
        Sm[a3] = csubf(A1, v);
    }
}

__global__ __launch_bounds__(1024) __attribute__((amdgpu_waves_per_eu(4, 4)))
void converse_main(const float* __restrict__ x, const float* __restrict__ bias,
                   const float2* __restrict__ KA, const float2* __restrict__ KB,
                   float* __restrict__ out)
{
    __shared__ float2 S[128 * ST2];
    __shared__ float2 TW[64];

    const int tid = threadIdx.x;
    const int bc  = blockIdx.x;       // [0,256) = b*64 + c
    const int c   = bc & 63;

    if (tid < 64) {
        float s_, c_;
        __sincosf(-6.28318530717958647692f * (float)tid * (1.0f/128.0f), &s_, &c_);
        TW[tid] = make_float2(c_, s_);
    }

    // ---- load x[b,c] as {x, 0} (contiguous float2 writes, conflict-free) ----
    const float* xp = x + (size_t)bc * 16384;
    #pragma unroll
    for (int it = 0; it < 16; ++it) {
        int n = it * 1024 + tid;
        S[(n >> 7) * ST2 + (n & 127)] = make_float2(xp[n], 0.0f);
    }

    // ---- prefetch KA into regs; loads ride across the whole forward FFT ----
    const float2* KpA = KA + (size_t)c * 16384;
    const float2* KpB = KB + (size_t)c * 16384;
    const int nn = tid & 127;
    const int t7 = tid >> 7;
    const int kbase = t7*256 + nn;
    float2 kr[16];
    #pragma unroll
    for (int it = 0; it < 8; ++it) {
        kr[2*it]   = KpA[it*2048 + kbase];
        kr[2*it+1] = KpA[it*2048 + kbase + 128];
    }
    barrier_lds();

    // ---- forward rows (along n): fused (0,1),(2,3),(4,5), single 6 ----
    fwd_pair<0,0>(S, TW, tid); barrier_lds();
    fwd_pair<0,2>(S, TW, tid); barrier_lds();
    fwd_pair<0,4>(S, TW, tid); barrier_lds();
    #pragma unroll
    for (int it = 0; it < 8; ++it) {     // stage 6: pairs (2k,2k+1), twiddle 1
        int g = it*1024 + tid;
        int line = g & 127, k = g >> 7;
        int a = line*ST2 + 2*k;
        float2 u = S[a], v = S[a+1];
        S[a]   = caddf(u, v);
        S[a+1] = csubf(u, v);
    }
    barrier_lds();

    // ---- forward cols (along m): fused (0,1),(2,3),(4,5) ----
    fwd_pair<1,0>(S, TW, tid); barrier_lds();
    fwd_pair<1,2>(S, TW, tid); barrier_lds();
    fwd_pair<1,4>(S, TW, tid); barrier_lds();

    // ---- forward col stage 6 into registers (spectrum kept for both passes) ----
    float2 sA[8], sB[8];
    #pragma unroll
    for (int it = 0; it < 8; ++it) {
        int g = it*1024 + tid;
        int nnl = g & 127, j = g >> 7;
        int a = (2*j)*ST2 + nnl;
        float2 u = S[a], v = S[a + ST2];
        sA[it] = caddf(u, v);
        sB[it] = csubf(u, v);
    }
    // no barrier needed: each thread re-writes only its own addresses in the mult

    const float bv = bias[c];
    float* op = out + (size_t)bc * 65536;

    // ================= pass 0 (KA, even output rows) =================
    #pragma unroll
    for (int it = 0; it < 8; ++it) {     // K-mult fused with inverse col stage 0
        int j = it*8 + t7;
        float2 w0 = cmulf(sA[it], kr[2*it]);
        float2 w1 = cmulf(sB[it], kr[2*it+1]);
        int a = (2*j)*ST2 + nn;
        S[a]       = caddf(w0, w1);
        S[a + ST2] = csubf(w0, w1);
    }
    // prefetch KB into the same regs; rides across pass-0 inverse FFT + stores
    #pragma unroll
    for (int it = 0; it < 8; ++it) {
        kr[2*it]   = KpB[it*2048 + kbase];
        kr[2*it+1] = KpB[it*2048 + kbase + 128];
    }
    barrier_lds();

    inv_pair<1,1>(S, TW, tid); barrier_lds();
    inv_pair<1,3>(S, TW, tid); barrier_lds();
    inv_pair<1,5>(S, TW, tid); barrier_lds();
    inv_pair<0,0>(S, TW, tid); barrier_lds();
    inv_pair<0,2>(S, TW, tid); barrier_lds();
    inv_pair<0,4>(S, TW, tid); barrier_lds();

    #pragma unroll
    for (int it = 0; it < 8; ++it) {     // inverse row stage 6 fused with store
        int g = it*1024 + tid;
        int j = g & 63, m = g >> 6;
        int a = m*ST2 + j;
        float2 u = S[a], v = S[a + 64];
        float2 t = cmulcf(v, TW[j]);
        float2 o0 = caddf(u, t);
        float2 o1 = csubf(u, t);
        size_t ro = (size_t)(2*m) * 256;
        *(float2*)(op + ro + 2*j)       = make_float2(o0.x + bv, o0.y + bv);
        *(float2*)(op + ro + 2*j + 128) = make_float2(o1.x + bv, o1.y + bv);
    }
    barrier_lds();   // protect S (ds_reads retired); global stores stay in flight

    // ================= pass 1 (KB, odd output rows) =================
    #pragma unroll
    for (int it = 0; it < 8; ++it) {
        int j = it*8 + t7;
        float2 w0 = cmulf(sA[it], kr[2*it]);
        float2 w1 = cmulf(sB[it], kr[2*it+1]);
        int a = (2*j)*ST2 + nn;
        S[a]       = caddf(w0, w1);
        S[a + ST2] = csubf(w0, w1);
    }
    barrier_lds();

    inv_pair<1,1>(S, TW, tid); barrier_lds();
    inv_pair<1,3>(S, TW, tid); barrier_lds();
    inv_pair<1,5>(S, TW, tid); barrier_lds();
    inv_pair<0,0>(S, TW, tid); barrier_lds();
    inv_pair<0,2>(S, TW, tid); barrier_lds();
    inv_pair<0,4>(S, TW, tid); barrier_lds();

    #pragma unroll
    for (int it = 0; it < 8; ++it) {
        int g = it*1024 + tid;
        int j = g & 63, m = g >> 6;
        int a = m*ST2 + j;
        float2 u = S[a], v = S[a + 64];
        float2 t = cmulcf(v, TW[j]);
        float2 o0 = caddf(u, t);
        float2 o1 = csubf(u, t);
        size_t ro = (size_t)(2*m + 1) * 256;
        *(float2*)(op + ro + 2*j)       = make_float2(o0.x + bv, o0.y + bv);
        *(float2*)(op + ro + 2*j + 128) = make_float2(o1.x + bv, o1.y + bv);
    }
}

extern "C" void kernel_launch(void* const* d_in, const int* in_sizes, int n_in,
                              void* d_out, int out_size, void* d_ws, size_t ws_size,
                              hipStream_t stream)
{
    const float* x      = (const float*)d_in[0];   // [4,64,128,128]
    const float* weight = (const float*)d_in[1];   // [1,64,5,5]
    const float* bias   = (const float*)d_in[2];   // [1,64,1,1]
    const float* lam    = (const float*)d_in[3];   // [1,1,1,1]
    float* out = (float*)d_out;                    // [4,64,256,256]

    float2* KA = (float2*)d_ws;                    // 8 MB
    float2* KB = KA + (size_t)64 * 16384;          // 8 MB

    hipLaunchKernelGGL(precompute_K, dim3(4096), dim3(256), 0, stream,
                       weight, lam, KA, KB);
    hipLaunchKernelGGL(converse_main, dim3(256), dim3(1024), 0, stream,
                       x, bias, KA, KB, out);
}

// Round 6
// 132.598 us; speedup vs baseline: 1.0798x; 1.0798x over previous
//
#include <hip/hip_runtime.h>
#include <math.h>

// Converse2D (USRNet closed-form prox), s=2, B=4, C=64, H=W=128, K=5.
// Per (b,c): 1 fwd 128x128 FFT, then two {K-mult + inv FFT} passes packing the
// 4 output polyphases. Fused radix-2 stage pairs (radix-4 traffic), float2 LDS.
//
// R1: precompute_K stores made output-contiguous (brev on input side).
// R2: launch_bounds(.,4) -> no effect.
// R3: LDS-only barriers + K prefetch into regs; precompute LDS-free.
// R4/R5: amdgpu_waves_per_eu attempts -> IGNORED by toolchain (VGPR stayed 64,
//     traffic identical, dur delta = pure clocks).
// R6: stop fighting the allocator; lower peak register DEMAND below the 64-VGPR
//     budget instead. The only >64 window was kr[16] (32 regs, prefetched K)
//     overlapping sA/sB (32 regs, retained spectrum) + FFT temps across pass-0's
//     inverse -> ~20 regs scratch-spilled (the +50MiB phantom WRITE_SIZE and
//     the latency gap). Changes:
//       (a) fuse col-stage-6 with pass-0 mult: kr[2it] dies as sA/sB[it] born
//           (elementwise peak ~34+temps);
//       (b) no KB prefetch: pass-1 mult loads KB inline (coalesced, one vmcnt
//           wait ~1-2us) so pass-0 inverse runs at sA/sB(32)+temps(~26) < 64.
//     Signature to verify: WRITE_SIZE 114MiB -> ~64-70MiB.

struct cx { float x, y; };
__device__ __forceinline__ cx cmul(cx a, cx b){ return cx{a.x*b.x - a.y*b.y, a.x*b.y + a.y*b.x}; }
__device__ __forceinline__ cx cadd(cx a, cx b){ return cx{a.x+b.x, a.y+b.y}; }
__device__ __forceinline__ cx csub(cx a, cx b){ return cx{a.x-b.x, a.y-b.y}; }
__device__ __forceinline__ cx cconj(cx a){ return cx{a.x, -a.y}; }
__device__ __forceinline__ cx cscale(cx a, float s){ return cx{a.x*s, a.y*s}; }

__device__ __forceinline__ float2 cmulf(float2 a, float2 b){
    return make_float2(a.x*b.x - a.y*b.y, a.x*b.y + a.y*b.x);
}
__device__ __forceinline__ float2 cmulcf(float2 a, float2 b){ // a * conj(b)
    return make_float2(a.x*b.x + a.y*b.y, a.y*b.x - a.x*b.y);
}
__device__ __forceinline__ float2 caddf(float2 a, float2 b){ return make_float2(a.x+b.x, a.y+b.y); }
__device__ __forceinline__ float2 csubf(float2 a, float2 b){ return make_float2(a.x-b.x, a.y-b.y); }

// LDS-only barrier: waits ds ops, leaves global loads/stores in flight.
__device__ __forceinline__ void barrier_lds(){
    __builtin_amdgcn_sched_barrier(0);
    asm volatile("s_waitcnt lgkmcnt(0)" ::: "memory");
    __builtin_amdgcn_s_barrier();
    __builtin_amdgcn_sched_barrier(0);
}

// ---------------- precompute_K: 1 point/thread, no LDS (R3-proven) ----------------
__global__ __launch_bounds__(256, 4)
void precompute_K(const float* __restrict__ weight, const float* __restrict__ lam_ptr,
                  float2* __restrict__ KA, float2* __restrict__ KB)
{
    const int tid = threadIdx.x;
    const int c   = blockIdx.x >> 6;                   // 64 blocks per channel
    const int p   = ((blockIdx.x & 63) << 8) + tid;    // 0..16383 (output index)
    const int qb = p >> 7, rb = p & 127;
    const int q = (int)(__brev((unsigned)qb) >> 25);   // brev on INPUT side
    const int r = (int)(__brev((unsigned)rb) >> 25);

    const float th = -6.28318530717958647692f * (1.0f/256.0f);
    float s1,c1, s2,c2, sq1,cq1, sq2,cq2;
    __sincosf(th * (float)r,       &s1,  &c1);
    __sincosf(th * (float)(2*r),   &s2,  &c2);
    __sincosf(th * (float)q,       &sq1, &cq1);
    __sincosf(th * (float)(2*q),   &sq2, &cq2);

    // er[t] = e^{-2*pi*i*r(t-2)/256}, t=0..4
    cx er[5] = { cx{c2,-s2}, cx{c1,-s1}, cx{1.f,0.f}, cx{c1,s1}, cx{c2,s2} };
    cx eq[5] = { cx{cq2,-sq2}, cx{cq1,-sq1}, cx{1.f,0.f}, cx{cq1,sq1}, cx{cq2,sq2} };

    const float lam = lam_ptr[0];
    const float* wc = weight + c*25;                   // wave-uniform -> s_loads

    cx P0[5], P1[5];
    #pragma unroll
    for (int a = 0; a < 5; ++a) {
        cx p0{0.f,0.f}, p1{0.f,0.f};
        #pragma unroll
        for (int b = 0; b < 5; ++b) {
            cx t = cscale(er[b], wc[a*5 + b]);
            p0 = cadd(p0, t);
            p1 = (b & 1) ? csub(p1, t) : cadd(p1, t);
        }
        P0[a] = p0; P1[a] = p1;
    }
    cx F00{0.f,0.f}, F01{0.f,0.f}, F10{0.f,0.f}, F11{0.f,0.f};
    #pragma unroll
    for (int a = 0; a < 5; ++a) {
        cx t0 = cmul(eq[a], P0[a]);
        cx t1 = cmul(eq[a], P1[a]);
        F00 = cadd(F00, t0); F01 = cadd(F01, t1);
        if (a & 1) { F10 = csub(F10, t0); F11 = csub(F11, t1); }
        else       { F10 = cadd(F10, t0); F11 = cadd(F11, t1); }
    }
    const float cq = cq1, sq = sq1, cr = c1, sr = s1;
    cx Du[2] = { cx{1.f+cq,  sq}, cx{1.f-cq, -sq} };
    cx Dv[2] = { cx{1.f+cr,  sr}, cx{1.f-cr, -sr} };
    cx Fm[2][2] = { {F00, F01}, {F10, F11} };
    cx R[2][2];
    float invW = 0.f;
    cx M{0.f,0.f};
    #pragma unroll
    for (int i = 0; i < 2; ++i)
      #pragma unroll
      for (int k = 0; k < 2; ++k) {
        cx fb = Fm[i][k];
        cx Rik = cadd(cconj(fb), cscale(cmul(Du[i], Dv[k]), lam));
        R[i][k] = Rik;
        invW += 0.25f * (fb.x*fb.x + fb.y*fb.y);
        M = cadd(M, cscale(cmul(fb, Rik), 0.25f));
      }
    cx V = cscale(M, 1.0f / (invW + lam));
    float inv_lam = 1.0f / lam;
    cx G[2][2];
    #pragma unroll
    for (int i = 0; i < 2; ++i)
      #pragma unroll
      for (int k = 0; k < 2; ++k)
        G[i][k] = cscale(csub(R[i][k], cmul(cconj(Fm[i][k]), V)), inv_lam);

    cx G00 = G[0][0], G01 = G[0][1], G10 = G[1][0], G11 = G[1][1];
    cx Gh00 = cadd(cadd(G00,G01), cadd(G10,G11));
    cx Gh01 = cadd(csub(G00,G01), csub(G10,G11));
    cx Gh10 = csub(cadd(G00,G01), cadd(G10,G11));
    cx Gh11 = csub(csub(G00,G01), csub(G10,G11));
    cx phq = cx{cq, -sq};
    cx phr = cx{cr, -sr};
    cx H0 = Gh00;
    cx H1 = cmul(Gh01, phr);
    cx H2 = cmul(Gh10, phq);
    cx H3 = cmul(Gh11, cmul(phq, phr));

    const float scale = 1.0f / 65536.0f;   // ifft 1/(128*128) and 1/4 polyphase mean
    float2 kAv = make_float2((H0.x - H1.y)*scale, (H0.y + H1.x)*scale);
    float2 kBv = make_float2((H2.x - H3.y)*scale, (H2.y + H3.x)*scale);
    int o = (c << 14) + p;                 // contiguous across tid -> coalesced
    KA[o] = kAv;
    KB[o] = kBv;
}

#define ST2 129   // float2 stride: odd -> both row & col passes at bank-bandwidth minimum

template<int AXIS> __device__ __forceinline__ int laddr(int line, int i){
    return AXIS ? (i*ST2 + line) : (line*ST2 + i);
}

// Forward DIF, fused stages (S, S+1). S in {0,2,4}. 4096 quartets, 4/thread.
template<int AXIS, int S>
__device__ __forceinline__ void fwd_pair(float2* Sm, const float2* TW, int tid)
{
    const int h  = 64 >> S;
    const int hh = 32 >> S;
    #pragma unroll
    for (int it = 0; it < 4; ++it) {
        int qid  = it*1024 + tid;
        int line = qid & 127;
        int t    = qid >> 7;
        int blk  = t >> (5 - S);
        int j    = t & (hh - 1);
        int i0   = (blk << (7 - S)) + j;
        int a0 = laddr<AXIS>(line, i0);
        int a1 = laddr<AXIS>(line, i0 + hh);
        int a2 = laddr<AXIS>(line, i0 + h);
        int a3 = laddr<AXIS>(line, i0 + h + hh);
        float2 e0 = Sm[a0], e1 = Sm[a1], e2 = Sm[a2], e3 = Sm[a3];
        float2 w0 = TW[j << S], w1 = TW[(j << S) + 32], w2 = TW[j << (S + 1)];
        float2 u0 = caddf(e0, e2), d0 = cmulf(csubf(e0, e2), w0);
        float2 u1 = caddf(e1, e3), d1 = cmulf(csubf(e1, e3), w1);
        Sm[a0] = caddf(u0, u1);
        Sm[a1] = cmulf(csubf(u0, u1), w2);
        Sm[a2] = caddf(d0, d1);
        Sm[a3] = cmulf(csubf(d0, d1), w2);
    }
}

// Inverse DIT, fused stages (S, S+1). conj twiddles.
template<int AXIS, int S>
__device__ __forceinline__ void inv_pair(float2* Sm, const float2* TW, int tid)
{
    const int h = 1 << S;
    #pragma unroll
    for (int it = 0; it < 4; ++it) {
        int qid  = it*1024 + tid;
        int line = qid & 127;
        int t    = qid >> 7;
        int blk  = t >> S;
        int j    = t & (h - 1);
        int base = (blk << (S + 2)) + j;
        int a0 = laddr<AXIS>(line, base);
        int a1 = laddr<AXIS>(line, base + h);
        int a2 = laddr<AXIS>(line, base + 2*h);
        int a3 = laddr<AXIS>(line, base + 3*h);
        float2 e0 = Sm[a0], e1 = Sm[a1], e2 = Sm[a2], e3 = Sm[a3];
        float2 cw0 = TW[j << (6 - S)];
        float2 cw1 = TW[j << (5 - S)];
        float2 cw2 = TW[(j << (5 - S)) + 32];
        float2 t1 = cmulcf(e1, cw0);
        float2 A0 = caddf(e0, t1), A1 = csubf(e0, t1);
        float2 t2 = cmulcf(e3, cw0);
        float2 A2 = caddf(e2, t2), A3 = csubf(e2, t2);
        float2 u = cmulcf(A2, cw1);
        Sm[a0] = caddf(A0, u);
        Sm[a2] = csubf(A0, u);
        float2 v = cmulcf(A3, cw2);
        Sm[a1] = caddf(A1, v);
        Sm[a3] = csubf(A1, v);
    }
}

__global__ __launch_bounds__(1024)
void converse_main(const float* __restrict__ x, const float* __restrict__ bias,
                   const float2* __restrict__ KA, const float2* __restrict__ KB,
                   float* __restrict__ out)
{
    __shared__ float2 S[128 * ST2];
    __shared__ float2 TW[64];

    const int tid = threadIdx.x;
    const int bc  = blockIdx.x;       // [0,256) = b*64 + c
    const int c   = bc & 63;

    if (tid < 64) {
        float s_, c_;
        __sincosf(-6.28318530717958647692f * (float)tid * (1.0f/128.0f), &s_, &c_);
        TW[tid] = make_float2(c_, s_);
    }

    // ---- load x[b,c] as {x, 0} (contiguous float2 writes, conflict-free) ----
    const float* xp = x + (size_t)bc * 16384;
    #pragma unroll
    for (int it = 0; it < 16; ++it) {
        int n = it * 1024 + tid;
        S[(n >> 7) * ST2 + (n & 127)] = make_float2(xp[n], 0.0f);
    }

    // ---- prefetch KA into regs; loads ride across the whole forward FFT ----
    // (sA/sB don't exist yet, so kr[16] fits comfortably in the 64-VGPR budget)
    const float2* KpA = KA + (size_t)c * 16384;
    const float2* KpB = KB + (size_t)c * 16384;
    const int nn = tid & 127;
    const int t7 = tid >> 7;
    const int kbase = t7*256 + nn;
    float2 kr[16];
    #pragma unroll
    for (int it = 0; it < 8; ++it) {
        kr[2*it]   = KpA[it*2048 + kbase];
        kr[2*it+1] = KpA[it*2048 + kbase + 128];
    }
    barrier_lds();

    // ---- forward rows (along n): fused (0,1),(2,3),(4,5), single 6 ----
    fwd_pair<0,0>(S, TW, tid); barrier_lds();
    fwd_pair<0,2>(S, TW, tid); barrier_lds();
    fwd_pair<0,4>(S, TW, tid); barrier_lds();
    #pragma unroll
    for (int it = 0; it < 8; ++it) {     // stage 6: pairs (2k,2k+1), twiddle 1
        int g = it*1024 + tid;
        int line = g & 127, k = g >> 7;
        int a = line*ST2 + 2*k;
        float2 u = S[a], v = S[a+1];
        S[a]   = caddf(u, v);
        S[a+1] = csubf(u, v);
    }
    barrier_lds();

    // ---- forward cols (along m): fused (0,1),(2,3),(4,5) ----
    fwd_pair<1,0>(S, TW, tid); barrier_lds();
    fwd_pair<1,2>(S, TW, tid); barrier_lds();
    fwd_pair<1,4>(S, TW, tid); barrier_lds();

    const float bv = bias[c];
    float* op = out + (size_t)bc * 65536;

    // ---- FUSED: forward col stage 6 + spectrum retain + pass-0 K-mult ----
    // kr[2it] dies in the same iteration sA/sB[it] are born: elementwise peak
    // stays ~34 regs + temps instead of 64 + temps (the old spill window).
    float2 sA[8], sB[8];
    #pragma unroll
    for (int it = 0; it < 8; ++it) {
        int j = it*8 + t7;
        int a = (2*j)*ST2 + nn;
        float2 u = S[a], v = S[a + ST2];
        float2 vA = caddf(u, v);
        float2 vB = csubf(u, v);
        sA[it] = vA;
        sB[it] = vB;
        float2 w0 = cmulf(vA, kr[2*it]);
        float2 w1 = cmulf(vB, kr[2*it+1]);
        S[a]       = caddf(w0, w1);       // own addresses: no barrier needed
        S[a + ST2] = csubf(w0, w1);
    }
    barrier_lds();

    // ================= pass 0 (KA, even output rows) =================
    // live regs here: sA/sB(32) + FFT temps only -- no K prefetch.
    inv_pair<1,1>(S, TW, tid); barrier_lds();
    inv_pair<1,3>(S, TW, tid); barrier_lds();
    inv_pair<1,5>(S, TW, tid); barrier_lds();
    inv_pair<0,0>(S, TW, tid); barrier_lds();
    inv_pair<0,2>(S, TW, tid); barrier_lds();
    inv_pair<0,4>(S, TW, tid); barrier_lds();

    #pragma unroll
    for (int it = 0; it < 8; ++it) {     // inverse row stage 6 fused with store
        int g = it*1024 + tid;
        int j = g & 63, m = g >> 6;
        int a = m*ST2 + j;
        float2 u = S[a], v = S[a + 64];
        float2 t = cmulcf(v, TW[j]);
        float2 o0 = caddf(u, t);
        float2 o1 = csubf(u, t);
        size_t ro = (size_t)(2*m) * 256;
        *(float2*)(op + ro + 2*j)       = make_float2(o0.x + bv, o0.y + bv);
        *(float2*)(op + ro + 2*j + 128) = make_float2(o1.x + bv, o1.y + bv);
    }
    barrier_lds();   // protect S (ds_reads retired); global stores stay in flight

    // ================= pass 1 (KB, odd output rows) =================
    // KB read inline (coalesced 512B/wave loads, one vmcnt wait) -- trades
    // ~1-2us of load latency for zero register-pressure overlap with sA/sB.
    #pragma unroll
    for (int it = 0; it < 8; ++it) {
        int j = it*8 + t7;
        float2 kb0 = KpB[it*2048 + kbase];
        float2 kb1 = KpB[it*2048 + kbase + 128];
        float2 w0 = cmulf(sA[it], kb0);
        float2 w1 = cmulf(sB[it], kb1);
        int a = (2*j)*ST2 + nn;
        S[a]       = caddf(w0, w1);
        S[a + ST2] = csubf(w0, w1);
    }
    barrier_lds();

    inv_pair<1,1>(S, TW, tid); barrier_lds();
    inv_pair<1,3>(S, TW, tid); barrier_lds();
    inv_pair<1,5>(S, TW, tid); barrier_lds();
    inv_pair<0,0>(S, TW, tid); barrier_lds();
    inv_pair<0,2>(S, TW, tid); barrier_lds();
    inv_pair<0,4>(S, TW, tid); barrier_lds();

    #pragma unroll
    for (int it = 0; it < 8; ++it) {
        int g = it*1024 + tid;
        int j = g & 63, m = g >> 6;
        int a = m*ST2 + j;
        float2 u = S[a], v = S[a + 64];
        float2 t = cmulcf(v, TW[j]);
        float2 o0 = caddf(u, t);
        float2 o1 = csubf(u, t);
        size_t ro = (size_t)(2*m + 1) * 256;
        *(float2*)(op + ro + 2*j)       = make_float2(o0.x + bv, o0.y + bv);
        *(float2*)(op + ro + 2*j + 128) = make_float2(o1.x + bv, o1.y + bv);
    }
}

extern "C" void kernel_launch(void* const* d_in, const int* in_sizes, int n_in,
                              void* d_out, int out_size, void* d_ws, size_t ws_size,
                              hipStream_t stream)
{
    const float* x      = (const float*)d_in[0];   // [4,64,128,128]
    const float* weight = (const float*)d_in[1];   // [1,64,5,5]
    const float* bias   = (const float*)d_in[2];   // [1,64,1,1]
    const float* lam    = (const float*)d_in[3];   // [1,1,1,1]
    float* out = (float*)d_out;                    // [4,64,256,256]

    float2* KA = (float2*)d_ws;                    // 8 MB
    float2* KB = KA + (size_t)64 * 16384;          // 8 MB

    hipLaunchKernelGGL(precompute_K, dim3(4096), dim3(256), 0, stream,
                       weight, lam, KA, KB);
    hipLaunchKernelGGL(converse_main, dim3(256), dim3(1024), 0, stream,
                       x, bias, KA, KB, out);
}

// Round 7
// 131.828 us; speedup vs baseline: 1.0861x; 1.0058x over previous
//
#include <hip/hip_runtime.h>
#include <math.h>

// Converse2D (USRNet closed-form prox), s=2, B=4, C=64, H=W=128, K=5.
// Per (b,c): 1 fwd 128x128 FFT, then two {K-mult + inv FFT} passes packing the
// 4 output polyphases. Fused radix-2 stage pairs (radix-4 traffic), float2 LDS.
//
// R1: precompute_K stores made output-contiguous (brev on input side).
// R2/R4/R5: allocator-attribute attempts -> ignored (VGPR pinned at 64).
// R3: LDS-only barriers + K prefetch into regs; precompute LDS-free.
// R6: converse spill fix by DEMAND reduction (fuse stage6+mult, kill KB
//     prefetch): WRITE 114->77MiB, FETCH 42->23MiB, dur -15%. CONFIRMED the
//     64-VGPR budget is immovable; fit the kernel inside it.
// R7: same cure for precompute_K (the remaining ~78us gap; per-thread live
//     state er/eq/P0/P1/F ~80 VGPRs > 64 -> spilling ~160MB of scratch).
//     Restructure: block = (channel, 512-pt slab); stage 1 builds P_a(R)
//     (the r-side 5-tap DFT, previously recomputed 128x redundantly per
//     channel) in LDS at rotated index rot(R)=(R>>1)|((R&1)<<7) so stage-2's
//     bit-reversed reads are 64 consecutive offsets per wave (bank-minimal);
//     stage 2 reads P0/P1 from LDS, lives in ~40 VGPRs, no spill.

struct cx { float x, y; };
__device__ __forceinline__ cx cmul(cx a, cx b){ return cx{a.x*b.x - a.y*b.y, a.x*b.y + a.y*b.x}; }
__device__ __forceinline__ cx cadd(cx a, cx b){ return cx{a.x+b.x, a.y+b.y}; }
__device__ __forceinline__ cx csub(cx a, cx b){ return cx{a.x-b.x, a.y-b.y}; }
__device__ __forceinline__ cx cconj(cx a){ return cx{a.x, -a.y}; }
__device__ __forceinline__ cx cscale(cx a, float s){ return cx{a.x*s, a.y*s}; }

__device__ __forceinline__ float2 cmulf(float2 a, float2 b){
    return make_float2(a.x*b.x - a.y*b.y, a.x*b.y + a.y*b.x);
}
__device__ __forceinline__ float2 cmulcf(float2 a, float2 b){ // a * conj(b)
    return make_float2(a.x*b.x + a.y*b.y, a.y*b.x - a.x*b.y);
}
__device__ __forceinline__ float2 caddf(float2 a, float2 b){ return make_float2(a.x+b.x, a.y+b.y); }
__device__ __forceinline__ float2 csubf(float2 a, float2 b){ return make_float2(a.x-b.x, a.y-b.y); }

// LDS-only barrier: waits ds ops, leaves global loads/stores in flight.
__device__ __forceinline__ void barrier_lds(){
    __builtin_amdgcn_sched_barrier(0);
    asm volatile("s_waitcnt lgkmcnt(0)" ::: "memory");
    __builtin_amdgcn_s_barrier();
    __builtin_amdgcn_sched_barrier(0);
}

// ---------------- precompute_K v3: LDS P-staging, 2 points/thread ----------------
// Grid: 2048 blocks = 64 channels x 32 slabs (512 output points each).
__global__ __launch_bounds__(256)
void precompute_K(const float* __restrict__ weight, const float* __restrict__ lam_ptr,
                  float2* __restrict__ KA, float2* __restrict__ KB)
{
    __shared__ float2 P[5 * 256];      // P[a][rot(R)], R in [0,256)

    const int tid  = threadIdx.x;
    const int c    = blockIdx.x >> 5;  // channel
    const int slab = blockIdx.x & 31;  // 512-point slab of the 16384-pt table

    const float* wc = weight + c*25;   // wave-uniform -> scalar loads
    const float lam = lam_ptr[0];
    const float th  = -6.28318530717958647692f * (1.0f/256.0f);

    // ---- stage 1: P_a(R) = sum_b w[a][b] * e^{-2pi i R(b-2)/256}, R = tid ----
    {
        float s1,c1, s2,c2;
        __sincosf(th * (float)tid,     &s1, &c1);
        __sincosf(th * (float)(2*tid), &s2, &c2);
        cx er[5] = { cx{c2,-s2}, cx{c1,-s1}, cx{1.f,0.f}, cx{c1,s1}, cx{c2,s2} };
        const int rs = (tid >> 1) | ((tid & 1) << 7);   // rot(R)
        #pragma unroll
        for (int a = 0; a < 5; ++a) {
            float px = 0.f, py = 0.f;
            #pragma unroll
            for (int b = 0; b < 5; ++b) {
                float w = wc[a*5 + b];
                px += w * er[b].x;
                py += w * er[b].y;
            }
            P[a*256 + rs] = make_float2(px, py);
        }
    }
    __syncthreads();

    const float scale = 1.0f / 65536.0f;  // ifft 1/(128*128) and 1/4 polyphase mean

    #pragma unroll 1
    for (int it = 0; it < 2; ++it) {
        const int p  = slab*512 + it*256 + tid;        // output (bit-rev-domain) idx
        const int qb = p >> 7, rb = p & 127;
        const int q = (int)(__brev((unsigned)qb) >> 25);  // brev on INPUT side
        const int r = (int)(__brev((unsigned)rb) >> 25);
        const int rr = (r >> 1) | ((r & 1) << 7);      // rot(r); rot(r+128)=rr+64

        float sq1,cq1, sq2,cq2;
        __sincosf(th * (float)q,     &sq1, &cq1);      // q wave-uniform
        __sincosf(th * (float)(2*q), &sq2, &cq2);
        cx eq[5] = { cx{cq2,-sq2}, cx{cq1,-sq1}, cx{1.f,0.f}, cx{cq1,sq1}, cx{cq2,sq2} };

        // F[i][k] from LDS-staged P: 10 cmuls + signed adds
        cx F00{0.f,0.f}, F01{0.f,0.f}, F10{0.f,0.f}, F11{0.f,0.f};
        #pragma unroll
        for (int a = 0; a < 5; ++a) {
            float2 p0 = P[a*256 + rr];
            float2 p1 = P[a*256 + rr + 64];
            cx t0 = cmul(eq[a], cx{p0.x, p0.y});
            cx t1 = cmul(eq[a], cx{p1.x, p1.y});
            F00 = cadd(F00, t0); F01 = cadd(F01, t1);
            if (a & 1) { F10 = csub(F10, t0); F11 = csub(F11, t1); }
            else       { F10 = cadd(F10, t0); F11 = cadd(F11, t1); }
        }

        const float cq = cq1, sq = sq1, cr = 0.f, sr = 0.f; // cr/sr set below
        (void)cr; (void)sr;
        // r-side phase for Dv and final phases: e^{-2pi i r/256}
        float sr1, cr1;
        __sincosf(th * (float)r, &sr1, &cr1);

        cx Du[2] = { cx{1.f+cq,  sq}, cx{1.f-cq, -sq} };
        cx Dv[2] = { cx{1.f+cr1,  sr1}, cx{1.f-cr1, -sr1} };
        cx Fm[2][2] = { {F00, F01}, {F10, F11} };
        cx R[2][2];
        float invW = 0.f;
        cx M{0.f,0.f};
        #pragma unroll
        for (int i = 0; i < 2; ++i)
          #pragma unroll
          for (int k = 0; k < 2; ++k) {
            cx fb = Fm[i][k];
            cx Rik = cadd(cconj(fb), cscale(cmul(Du[i], Dv[k]), lam));
            R[i][k] = Rik;
            invW += 0.25f * (fb.x*fb.x + fb.y*fb.y);
            M = cadd(M, cscale(cmul(fb, Rik), 0.25f));
          }
        cx V = cscale(M, 1.0f / (invW + lam));
        float inv_lam = 1.0f / lam;
        cx G[2][2];
        #pragma unroll
        for (int i = 0; i < 2; ++i)
          #pragma unroll
          for (int k = 0; k < 2; ++k)
            G[i][k] = cscale(csub(R[i][k], cmul(cconj(Fm[i][k]), V)), inv_lam);

        cx G00 = G[0][0], G01 = G[0][1], G10 = G[1][0], G11 = G[1][1];
        cx Gh00 = cadd(cadd(G00,G01), cadd(G10,G11));
        cx Gh01 = cadd(csub(G00,G01), csub(G10,G11));
        cx Gh10 = csub(cadd(G00,G01), cadd(G10,G11));
        cx Gh11 = csub(csub(G00,G01), csub(G10,G11));
        cx phq = cx{cq, -sq};
        cx phr = cx{cr1, -sr1};
        cx H0 = Gh00;
        cx H1 = cmul(Gh01, phr);
        cx H2 = cmul(Gh10, phq);
        cx H3 = cmul(Gh11, cmul(phq, phr));

        float2 kAv = make_float2((H0.x - H1.y)*scale, (H0.y + H1.x)*scale);
        float2 kBv = make_float2((H2.x - H3.y)*scale, (H2.y + H3.x)*scale);
        const int o = (c << 14) + p;       // contiguous across tid -> coalesced
        KA[o] = kAv;
        KB[o] = kBv;
    }
}

#define ST2 129   // float2 stride: odd -> both row & col passes at bank-bandwidth minimum

template<int AXIS> __device__ __forceinline__ int laddr(int line, int i){
    return AXIS ? (i*ST2 + line) : (line*ST2 + i);
}

// Forward DIF, fused stages (S, S+1). S in {0,2,4}. 4096 quartets, 4/thread.
template<int AXIS, int S>
__device__ __forceinline__ void fwd_pair(float2* Sm, const float2* TW, int tid)
{
    const int h  = 64 >> S;
    const int hh = 32 >> S;
    #pragma unroll
    for (int it = 0; it < 4; ++it) {
        int qid  = it*1024 + tid;
        int line = qid & 127;
        int t    = qid >> 7;
        int blk  = t >> (5 - S);
        int j    = t & (hh - 1);
        int i0   = (blk << (7 - S)) + j;
        int a0 = laddr<AXIS>(line, i0);
        int a1 = laddr<AXIS>(line, i0 + hh);
        int a2 = laddr<AXIS>(line, i0 + h);
        int a3 = laddr<AXIS>(line, i0 + h + hh);
        float2 e0 = Sm[a0], e1 = Sm[a1], e2 = Sm[a2], e3 = Sm[a3];
        float2 w0 = TW[j << S], w1 = TW[(j << S) + 32], w2 = TW[j << (S + 1)];
        float2 u0 = caddf(e0, e2), d0 = cmulf(csubf(e0, e2), w0);
        float2 u1 = caddf(e1, e3), d1 = cmulf(csubf(e1, e3), w1);
        Sm[a0] = caddf(u0, u1);
        Sm[a1] = cmulf(csubf(u0, u1), w2);
        Sm[a2] = caddf(d0, d1);
        Sm[a3] = cmulf(csubf(d0, d1), w2);
    }
}

// Inverse DIT, fused stages (S, S+1). conj twiddles.
template<int AXIS, int S>
__device__ __forceinline__ void inv_pair(float2* Sm, const float2* TW, int tid)
{
    const int h = 1 << S;
    #pragma unroll
    for (int it = 0; it < 4; ++it) {
        int qid  = it*1024 + tid;
        int line = qid & 127;
        int t    = qid >> 7;
        int blk  = t >> S;
        int j    = t & (h - 1);
        int base = (blk << (S + 2)) + j;
        int a0 = laddr<AXIS>(line, base);
        int a1 = laddr<AXIS>(line, base + h);
        int a2 = laddr<AXIS>(line, base + 2*h);
        int a3 = laddr<AXIS>(line, base + 3*h);
        float2 e0 = Sm[a0], e1 = Sm[a1], e2 = Sm[a2], e3 = Sm[a3];
        float2 cw0 = TW[j << (6 - S)];
        float2 cw1 = TW[j << (5 - S)];
        float2 cw2 = TW[(j << (5 - S)) + 32];
        float2 t1 = cmulcf(e1, cw0);
        float2 A0 = caddf(e0, t1), A1 = csubf(e0, t1);
        float2 t2 = cmulcf(e3, cw0);
        float2 A2 = caddf(e2, t2), A3 = csubf(e2, t2);
        float2 u = cmulcf(A2, cw1);
        Sm[a0] = caddf(A0, u);
        Sm[a2] = csubf(A0, u);
        float2 v = cmulcf(A3, cw2);
        Sm[a1] = caddf(A1, v);
        Sm[a3] = csubf(A1, v);
    }
}

__global__ __launch_bounds__(1024)
void converse_main(const float* __restrict__ x, const float* __restrict__ bias,
                   const float2* __restrict__ KA, const float2* __restrict__ KB,
                   float* __restrict__ out)
{
    __shared__ float2 S[128 * ST2];
    __shared__ float2 TW[64];

    const int tid = threadIdx.x;
    const int bc  = blockIdx.x;       // [0,256) = b*64 + c
    const int c   = bc & 63;

    if (tid < 64) {
        float s_, c_;
        __sincosf(-6.28318530717958647692f * (float)tid * (1.0f/128.0f), &s_, &c_);
        TW[tid] = make_float2(c_, s_);
    }

    // ---- load x[b,c] as {x, 0} (contiguous float2 writes, conflict-free) ----
    const float* xp = x + (size_t)bc * 16384;
    #pragma unroll
    for (int it = 0; it < 16; ++it) {
        int n = it * 1024 + tid;
        S[(n >> 7) * ST2 + (n & 127)] = make_float2(xp[n], 0.0f);
    }

    // ---- prefetch KA into regs; loads ride across the whole forward FFT ----
    // (sA/sB don't exist yet, so kr[16] fits comfortably in the 64-VGPR budget)
    const float2* KpA = KA + (size_t)c * 16384;
    const float2* KpB = KB + (size_t)c * 16384;
    const int nn = tid & 127;
    const int t7 = tid >> 7;
    const int kbase = t7*256 + nn;
    float2 kr[16];
    #pragma unroll
    for (int it = 0; it < 8; ++it) {
        kr[2*it]   = KpA[it*2048 + kbase];
        kr[2*it+1] = KpA[it*2048 + kbase + 128];
    }
    barrier_lds();

    // ---- forward rows (along n): fused (0,1),(2,3),(4,5), single 6 ----
    fwd_pair<0,0>(S, TW, tid); barrier_lds();
    fwd_pair<0,2>(S, TW, tid); barrier_lds();
    fwd_pair<0,4>(S, TW, tid); barrier_lds();
    #pragma unroll
    for (int it = 0; it < 8; ++it) {     // stage 6: pairs (2k,2k+1), twiddle 1
        int g = it*1024 + tid;
        int line = g & 127, k = g >> 7;
        int a = line*ST2 + 2*k;
        float2 u = S[a], v = S[a+1];
        S[a]   = caddf(u, v);
        S[a+1] = csubf(u, v);
    }
    barrier_lds();

    // ---- forward cols (along m): fused (0,1),(2,3),(4,5) ----
    fwd_pair<1,0>(S, TW, tid); barrier_lds();
    fwd_pair<1,2>(S, TW, tid); barrier_lds();
    fwd_pair<1,4>(S, TW, tid); barrier_lds();

    const float bv = bias[c];
    float* op = out + (size_t)bc * 65536;

    // ---- FUSED: forward col stage 6 + spectrum retain + pass-0 K-mult ----
    // kr[2it] dies in the same iteration sA/sB[it] are born: elementwise peak
    // stays ~34 regs + temps instead of 64 + temps (the old spill window).
    float2 sA[8], sB[8];
    #pragma unroll
    for (int it = 0; it < 8; ++it) {
        int j = it*8 + t7;
        int a = (2*j)*ST2 + nn;
        float2 u = S[a], v = S[a + ST2];
        float2 vA = caddf(u, v);
        float2 vB = csubf(u, v);
        sA[it] = vA;
        sB[it] = vB;
        float2 w0 = cmulf(vA, kr[2*it]);
        float2 w1 = cmulf(vB, kr[2*it+1]);
        S[a]       = caddf(w0, w1);       // own addresses: no barrier needed
        S[a + ST2] = csubf(w0, w1);
    }
    barrier_lds();

    // ================= pass 0 (KA, even output rows) =================
    // live regs here: sA/sB(32) + FFT temps only -- no K prefetch.
    inv_pair<1,1>(S, TW, tid); barrier_lds();
    inv_pair<1,3>(S, TW, tid); barrier_lds();
    inv_pair<1,5>(S, TW, tid); barrier_lds();
    inv_pair<0,0>(S, TW, tid); barrier_lds();
    inv_pair<0,2>(S, TW, tid); barrier_lds();
    inv_pair<0,4>(S, TW, tid); barrier_lds();

    #pragma unroll
    for (int it = 0; it < 8; ++it) {     // inverse row stage 6 fused with store
        int g = it*1024 + tid;
        int j = g & 63, m = g >> 6;
        int a = m*ST2 + j;
        float2 u = S[a], v = S[a + 64];
        float2 t = cmulcf(v, TW[j]);
        float2 o0 = caddf(u, t);
        float2 o1 = csubf(u, t);
        size_t ro = (size_t)(2*m) * 256;
        *(float2*)(op + ro + 2*j)       = make_float2(o0.x + bv, o0.y + bv);
        *(float2*)(op + ro + 2*j + 128) = make_float2(o1.x + bv, o1.y + bv);
    }
    barrier_lds();   // protect S (ds_reads retired); global stores stay in flight

    // ================= pass 1 (KB, odd output rows) =================
    // KB read inline (coalesced 512B/wave loads, one vmcnt wait) -- trades
    // ~1-2us of load latency for zero register-pressure overlap with sA/sB.
    #pragma unroll
    for (int it = 0; it < 8; ++it) {
        int j = it*8 + t7;
        float2 kb0 = KpB[it*2048 + kbase];
        float2 kb1 = KpB[it*2048 + kbase + 128];
        float2 w0 = cmulf(sA[it], kb0);
        float2 w1 = cmulf(sB[it], kb1);
        int a = (2*j)*ST2 + nn;
        S[a]       = caddf(w0, w1);
        S[a + ST2] = csubf(w0, w1);
    }
    barrier_lds();

    inv_pair<1,1>(S, TW, tid); barrier_lds();
    inv_pair<1,3>(S, TW, tid); barrier_lds();
    inv_pair<1,5>(S, TW, tid); barrier_lds();
    inv_pair<0,0>(S, TW, tid); barrier_lds();
    inv_pair<0,2>(S, TW, tid); barrier_lds();
    inv_pair<0,4>(S, TW, tid); barrier_lds();

    #pragma unroll
    for (int it = 0; it < 8; ++it) {
        int g = it*1024 + tid;
        int j = g & 63, m = g >> 6;
        int a = m*ST2 + j;
        float2 u = S[a], v = S[a + 64];
        float2 t = cmulcf(v, TW[j]);
        float2 o0 = caddf(u, t);
        float2 o1 = csubf(u, t);
        size_t ro = (size_t)(2*m + 1) * 256;
        *(float2*)(op + ro + 2*j)       = make_float2(o0.x + bv, o0.y + bv);
        *(float2*)(op + ro + 2*j + 128) = make_float2(o1.x + bv, o1.y + bv);
    }
}

extern "C" void kernel_launch(void* const* d_in, const int* in_sizes, int n_in,
                              void* d_out, int out_size, void* d_ws, size_t ws_size,
                              hipStream_t stream)
{
    const float* x      = (const float*)d_in[0];   // [4,64,128,128]
    const float* weight = (const float*)d_in[1];   // [1,64,5,5]
    const float* bias   = (const float*)d_in[2];   // [1,64,1,1]
    const float* lam    = (const float*)d_in[3];   // [1,1,1,1]
    float* out = (float*)d_out;                    // [4,64,256,256]

    float2* KA = (float2*)d_ws;                    // 8 MB
    float2* KB = KA + (size_t)64 * 16384;          // 8 MB

    hipLaunchKernelGGL(precompute_K, dim3(2048), dim3(256), 0, stream,
                       weight, lam, KA, KB);
    hipLaunchKernelGGL(converse_main, dim3(256), dim3(1024), 0, stream,
                       x, bias, KA, KB, out);
}

// Round 8
// 131.281 us; speedup vs baseline: 1.0906x; 1.0042x over previous
//
#include <hip/hip_runtime.h>
#include <math.h>

// Converse2D (USRNet closed-form prox), s=2, B=4, C=64, H=W=128, K=5.
// Per (b,c): 1 fwd 128x128 FFT, then two {K-mult + inv FFT} passes packing the
// 4 output polyphases. Fused radix-2 stage pairs (radix-4 traffic), float2 LDS.
//
// R1: precompute_K stores made output-contiguous (brev on input side).
// R2/R4/R5: allocator-attribute attempts -> ignored (VGPR pinned at 64).
// R3: LDS-only barriers + K prefetch into regs; precompute LDS-free.
// R6: converse spill fix by DEMAND reduction: WRITE 114->77MiB, FETCH 42->23MiB.
// R7: precompute LDS P-staging (r-side DFT shared): gap 78->~40us iso-clock.
// R8: finish the spill war on both kernels.
//  (a) precompute v4: algebraic compression so stage-2 provably fits 64 VGPRs.
//      G[ik] = conj(F[ik])*W + Du[i]Dv[k] with W=(1-V)/lam (exact identity);
//      DuDv sums collapse (Du0+Du1={2,0}, Du0-Du1=2wq) so each H =
//      conj(C)*W*phase + 4. ~165 VALU/pt (was ~300), live ~35 regs (was ~75).
//  (b) converse: park sB[5..7] in the 27KB LDS slack (24KB) -> pass-0 inverse
//      live set ~58 < 64, kills the residual ~13MiB phantom WRITE.

struct cx { float x, y; };
__device__ __forceinline__ cx cmul(cx a, cx b){ return cx{a.x*b.x - a.y*b.y, a.x*b.y + a.y*b.x}; }
__device__ __forceinline__ cx cadd(cx a, cx b){ return cx{a.x+b.x, a.y+b.y}; }
__device__ __forceinline__ cx csub(cx a, cx b){ return cx{a.x-b.x, a.y-b.y}; }
__device__ __forceinline__ cx cconj(cx a){ return cx{a.x, -a.y}; }
__device__ __forceinline__ cx cscale(cx a, float s){ return cx{a.x*s, a.y*s}; }

__device__ __forceinline__ float2 cmulf(float2 a, float2 b){
    return make_float2(a.x*b.x - a.y*b.y, a.x*b.y + a.y*b.x);
}
__device__ __forceinline__ float2 cmulcf(float2 a, float2 b){ // a * conj(b)
    return make_float2(a.x*b.x + a.y*b.y, a.y*b.x - a.x*b.y);
}
__device__ __forceinline__ float2 caddf(float2 a, float2 b){ return make_float2(a.x+b.x, a.y+b.y); }
__device__ __forceinline__ float2 csubf(float2 a, float2 b){ return make_float2(a.x-b.x, a.y-b.y); }

// conj(w)*A + w*B  (the conjugate-symmetric pair term of a small DFT)
__device__ __forceinline__ cx conjpair(cx w, float2 A, float2 B){
    return cx{ w.x*(A.x+B.x) + w.y*(A.y-B.y),
               w.x*(A.y+B.y) - w.y*(A.x-B.x) };
}

// LDS-only barrier: waits ds ops, leaves global loads/stores in flight.
__device__ __forceinline__ void barrier_lds(){
    __builtin_amdgcn_sched_barrier(0);
    asm volatile("s_waitcnt lgkmcnt(0)" ::: "memory");
    __builtin_amdgcn_s_barrier();
    __builtin_amdgcn_sched_barrier(0);
}

// ---------------- precompute_K v4: LDS P-staging + compressed algebra ----------------
// Grid: 2048 blocks = 64 channels x 32 slabs (512 output points each).
__global__ __launch_bounds__(256)
void precompute_K(const float* __restrict__ weight, const float* __restrict__ lam_ptr,
                  float2* __restrict__ KA, float2* __restrict__ KB)
{
    __shared__ float2 P[5 * 256];      // P[a][rot(R)], R in [0,256)

    const int tid  = threadIdx.x;
    const int c    = blockIdx.x >> 5;  // channel
    const int slab = blockIdx.x & 31;  // 512-point slab of the 16384-pt table

    const float* wc = weight + c*25;   // wave-uniform -> scalar loads
    const float lam = lam_ptr[0];
    const float inv_lam = 1.0f / lam;
    const float th  = -6.28318530717958647692f * (1.0f/256.0f);

    // ---- stage 1: P_a(R) = sum_b w[a][b] * e^{-2pi i R(b-2)/256}, R = tid ----
    {
        float s1,c1, s2,c2;
        __sincosf(th * (float)tid,     &s1, &c1);
        __sincosf(th * (float)(2*tid), &s2, &c2);
        cx er[5] = { cx{c2,-s2}, cx{c1,-s1}, cx{1.f,0.f}, cx{c1,s1}, cx{c2,s2} };
        const int rs = (tid >> 1) | ((tid & 1) << 7);   // rot(R)
        #pragma unroll
        for (int a = 0; a < 5; ++a) {
            float px = 0.f, py = 0.f;
            #pragma unroll
            for (int b = 0; b < 5; ++b) {
                float w = wc[a*5 + b];
                px += w * er[b].x;
                py += w * er[b].y;
            }
            P[a*256 + rs] = make_float2(px, py);
        }
    }
    __syncthreads();

    const float scale = 1.0f / 65536.0f;  // ifft 1/(128*128) and 1/4 polyphase mean

    #pragma unroll 1
    for (int it = 0; it < 2; ++it) {
        const int p  = slab*512 + it*256 + tid;        // output (bit-rev-domain) idx
        const int qb = p >> 7, rb = p & 127;
        const int q = (int)(__brev((unsigned)qb) >> 25);  // brev on INPUT side
        const int r = (int)(__brev((unsigned)rb) >> 25);
        const int rr = (r >> 1) | ((r & 1) << 7);      // rot(r); rot(r+128)=rr+64

        float sq1,cq1, sq2,cq2, sr1,cr1;
        __sincosf(th * (float)q,     &sq1, &cq1);      // q wave-uniform
        __sincosf(th * (float)(2*q), &sq2, &cq2);
        __sincosf(th * (float)r,     &sr1, &cr1);
        const cx w1{cq1, sq1};    // e^{-2pi i q/256}
        const cx w2{cq2, sq2};    // e^{-2pi i 2q/256}
        const cx wr{cr1, sr1};    // e^{-2pi i r/256}

        // ---- F[i][k] from LDS-staged P (P0 = P(r), P1 = P(r+128)) ----
        // F00 = P0[2] + [conj(w1)P0[1]+w1 P0[3]] + [conj(w2)P0[0]+w2 P0[4]]
        // F10 = P0[2] -        (same B1)         +        (same B2)
        float2 p0_0 = P[0*256+rr], p1_0 = P[0*256+rr+64];
        float2 p0_1 = P[1*256+rr], p1_1 = P[1*256+rr+64];
        float2 p0_2 = P[2*256+rr], p1_2 = P[2*256+rr+64];
        float2 p0_3 = P[3*256+rr], p1_3 = P[3*256+rr+64];
        float2 p0_4 = P[4*256+rr], p1_4 = P[4*256+rr+64];
        cx B1 = conjpair(w1, p0_1, p0_3);
        cx B2 = conjpair(w2, p0_0, p0_4);
        cx m0 = cx{p0_2.x, p0_2.y};
        cx F00 = cadd(cadd(m0, B1), B2);
        cx F10 = cadd(csub(m0, B1), B2);
        cx D1 = conjpair(w1, p1_1, p1_3);
        cx D2 = conjpair(w2, p1_0, p1_4);
        cx m1 = cx{p1_2.x, p1_2.y};
        cx F01 = cadd(cadd(m1, D1), D2);
        cx F11 = cadd(csub(m1, D1), D2);

        // ---- compressed closed form ----
        // M = 0.25*(SF2 + lam*T), invW = 0.25*SF2, V = M/(invW+lam), W=(1-V)/lam
        float SF2 = F00.x*F00.x + F00.y*F00.y + F01.x*F01.x + F01.y*F01.y
                  + F10.x*F10.x + F10.y*F10.y + F11.x*F11.x + F11.y*F11.y;
        cx Du0{1.f+cq1,  sq1}, Du1{1.f-cq1, -sq1};
        cx Dv0{1.f+cr1,  sr1}, Dv1{1.f-cr1, -sr1};
        cx T = cadd(cmul(Du0, cadd(cmul(F00,Dv0), cmul(F01,Dv1))),
                    cmul(Du1, cadd(cmul(F10,Dv0), cmul(F11,Dv1))));
        float invW = 0.25f * SF2;
        cx M{invW + 0.25f*lam*T.x, 0.25f*lam*T.y};
        float idn = 1.0f / (invW + lam);
        cx V{M.x*idn, M.y*idn};
        cx W{(1.f - V.x)*inv_lam, -V.y*inv_lam};

        // butterfly of F (the Gh combos' conj-part arguments)
        cx Sa = cadd(F00,F01), Sb = cadd(F10,F11);
        cx Da = csub(F00,F01), Db = csub(F10,F11);
        cx C00 = cadd(Sa,Sb), C10 = csub(Sa,Sb);
        cx C01 = cadd(Da,Db), C11 = csub(Da,Db);

        // H_p = conj(C_p)*W*phase_p + 4   (DuDv parts collapse exactly)
        cx WR  = cmul(W,  cconj(wr));
        cx WQ  = cmul(W,  cconj(w1));
        cx WQR = cmul(WQ, cconj(wr));
        cx H0 = cadd(cmul(cconj(C00), W  ), cx{4.f,0.f});
        cx H1 = cadd(cmul(cconj(C01), WR ), cx{4.f,0.f});
        cx H2 = cadd(cmul(cconj(C10), WQ ), cx{4.f,0.f});
        cx H3 = cadd(cmul(cconj(C11), WQR), cx{4.f,0.f});

        float2 kAv = make_float2((H0.x - H1.y)*scale, (H0.y + H1.x)*scale);
        float2 kBv = make_float2((H2.x - H3.y)*scale, (H2.y + H3.x)*scale);
        const int o = (c << 14) + p;       // contiguous across tid -> coalesced
        KA[o] = kAv;
        KB[o] = kBv;
    }
}

#define ST2 129   // float2 stride: odd -> both row & col passes at bank-bandwidth minimum

template<int AXIS> __device__ __forceinline__ int laddr(int line, int i){
    return AXIS ? (i*ST2 + line) : (line*ST2 + i);
}

// Forward DIF, fused stages (S, S+1). S in {0,2,4}. 4096 quartets, 4/thread.
template<int AXIS, int S>
__device__ __forceinline__ void fwd_pair(float2* Sm, const float2* TW, int tid)
{
    const int h  = 64 >> S;
    const int hh = 32 >> S;
    #pragma unroll
    for (int it = 0; it < 4; ++it) {
        int qid  = it*1024 + tid;
        int line = qid & 127;
        int t    = qid >> 7;
        int blk  = t >> (5 - S);
        int j    = t & (hh - 1);
        int i0   = (blk << (7 - S)) + j;
        int a0 = laddr<AXIS>(line, i0);
        int a1 = laddr<AXIS>(line, i0 + hh);
        int a2 = laddr<AXIS>(line, i0 + h);
        int a3 = laddr<AXIS>(line, i0 + h + hh);
        float2 e0 = Sm[a0], e1 = Sm[a1], e2 = Sm[a2], e3 = Sm[a3];
        float2 w0 = TW[j << S], w1 = TW[(j << S) + 32], w2 = TW[j << (S + 1)];
        float2 u0 = caddf(e0, e2), d0 = cmulf(csubf(e0, e2), w0);
        float2 u1 = caddf(e1, e3), d1 = cmulf(csubf(e1, e3), w1);
        Sm[a0] = caddf(u0, u1);
        Sm[a1] = cmulf(csubf(u0, u1), w2);
        Sm[a2] = caddf(d0, d1);
        Sm[a3] = cmulf(csubf(d0, d1), w2);
    }
}

// Inverse DIT, fused stages (S, S+1). conj twiddles.
template<int AXIS, int S>
__device__ __forceinline__ void inv_pair(float2* Sm, const float2* TW, int tid)
{
    const int h = 1 << S;
    #pragma unroll
    for (int it = 0; it < 4; ++it) {
        int qid  = it*1024 + tid;
        int line = qid & 127;
        int t    = qid >> 7;
        int blk  = t >> S;
        int j    = t & (h - 1);
        int base = (blk << (S + 2)) + j;
        int a0 = laddr<AXIS>(line, base);
        int a1 = laddr<AXIS>(line, base + h);
        int a2 = laddr<AXIS>(line, base + 2*h);
        int a3 = laddr<AXIS>(line, base + 3*h);
        float2 e0 = Sm[a0], e1 = Sm[a1], e2 = Sm[a2], e3 = Sm[a3];
        float2 cw0 = TW[j << (6 - S)];
        float2 cw1 = TW[j << (5 - S)];
        float2 cw2 = TW[(j << (5 - S)) + 32];
        float2 t1 = cmulcf(e1, cw0);
        float2 A0 = caddf(e0, t1), A1 = csubf(e0, t1);
        float2 t2 = cmulcf(e3, cw0);
        float2 A2 = caddf(e2, t2), A3 = csubf(e2, t2);
        float2 u = cmulcf(A2, cw1);
        Sm[a0] = caddf(A0, u);
        Sm[a2] = csubf(A0, u);
        float2 v = cmulcf(A3, cw2);
        Sm[a1] = caddf(A1, v);
        Sm[a3] = csubf(A1, v);
    }
}

__global__ __launch_bounds__(1024)
void converse_main(const float* __restrict__ x, const float* __restrict__ bias,
                   const float2* __restrict__ KA, const float2* __restrict__ KB,
                   float* __restrict__ out)
{
    __shared__ float2 S[128 * ST2];
    __shared__ float2 TW[64];
    __shared__ float2 SB[3 * 1024];   // sB[5..7] parked here (LDS slack, no spill)

    const int tid = threadIdx.x;
    const int bc  = blockIdx.x;       // [0,256) = b*64 + c
    const int c   = bc & 63;

    if (tid < 64) {
        float s_, c_;
        __sincosf(-6.28318530717958647692f * (float)tid * (1.0f/128.0f), &s_, &c_);
        TW[tid] = make_float2(c_, s_);
    }

    // ---- load x[b,c] as {x, 0} (contiguous float2 writes, conflict-free) ----
    const float* xp = x + (size_t)bc * 16384;
    #pragma unroll
    for (int it = 0; it < 16; ++it) {
        int n = it * 1024 + tid;
        S[(n >> 7) * ST2 + (n & 127)] = make_float2(xp[n], 0.0f);
    }

    // ---- prefetch KA into regs; loads ride across the whole forward FFT ----
    const float2* KpA = KA + (size_t)c * 16384;
    const float2* KpB = KB + (size_t)c * 16384;
    const int nn = tid & 127;
    const int t7 = tid >> 7;
    const int kbase = t7*256 + nn;
    float2 kr[16];
    #pragma unroll
    for (int it = 0; it < 8; ++it) {
        kr[2*it]   = KpA[it*2048 + kbase];
        kr[2*it+1] = KpA[it*2048 + kbase + 128];
    }
    barrier_lds();

    // ---- forward rows (along n): fused (0,1),(2,3),(4,5), single 6 ----
    fwd_pair<0,0>(S, TW, tid); barrier_lds();
    fwd_pair<0,2>(S, TW, tid); barrier_lds();
    fwd_pair<0,4>(S, TW, tid); barrier_lds();
    #pragma unroll
    for (int it = 0; it < 8; ++it) {     // stage 6: pairs (2k,2k+1), twiddle 1
        int g = it*1024 + tid;
        int line = g & 127, k = g >> 7;
        int a = line*ST2 + 2*k;
        float2 u = S[a], v = S[a+1];
        S[a]   = caddf(u, v);
        S[a+1] = csubf(u, v);
    }
    barrier_lds();

    // ---- forward cols (along m): fused (0,1),(2,3),(4,5) ----
    fwd_pair<1,0>(S, TW, tid); barrier_lds();
    fwd_pair<1,2>(S, TW, tid); barrier_lds();
    fwd_pair<1,4>(S, TW, tid); barrier_lds();

    const float bv = bias[c];
    float* op = out + (size_t)bc * 65536;

    // ---- FUSED: forward col stage 6 + spectrum retain + pass-0 K-mult ----
    // kr[2it] dies as sA/sB[it] are born; sB[5..7] go to LDS instead of regs
    // so pass-0 inverse's live set (sA 16 + sB 10 + temps ~32) fits 64 VGPRs.
    float2 sA[8], sB[5];
    #pragma unroll
    for (int it = 0; it < 8; ++it) {
        int j = it*8 + t7;
        int a = (2*j)*ST2 + nn;
        float2 u = S[a], v = S[a + ST2];
        float2 vA = caddf(u, v);
        float2 vB = csubf(u, v);
        sA[it] = vA;
        if (it < 5) sB[it] = vB;
        else        SB[(it-5)*1024 + tid] = vB;
        float2 w0 = cmulf(vA, kr[2*it]);
        float2 w1 = cmulf(vB, kr[2*it+1]);
        S[a]       = caddf(w0, w1);       // own addresses: no barrier needed
        S[a + ST2] = csubf(w0, w1);
    }
    barrier_lds();

    // ================= pass 0 (KA, even output rows) =================
    inv_pair<1,1>(S, TW, tid); barrier_lds();
    inv_pair<1,3>(S, TW, tid); barrier_lds();
    inv_pair<1,5>(S, TW, tid); barrier_lds();
    inv_pair<0,0>(S, TW, tid); barrier_lds();
    inv_pair<0,2>(S, TW, tid); barrier_lds();
    inv_pair<0,4>(S, TW, tid); barrier_lds();

    #pragma unroll
    for (int it = 0; it < 8; ++it) {     // inverse row stage 6 fused with store
        int g = it*1024 + tid;
        int j = g & 63, m = g >> 6;
        int a = m*ST2 + j;
        float2 u = S[a], v = S[a + 64];
        float2 t = cmulcf(v, TW[j]);
        float2 o0 = caddf(u, t);
        float2 o1 = csubf(u, t);
        size_t ro = (size_t)(2*m) * 256;
        *(float2*)(op + ro + 2*j)       = make_float2(o0.x + bv, o0.y + bv);
        *(float2*)(op + ro + 2*j + 128) = make_float2(o1.x + bv, o1.y + bv);
    }
    barrier_lds();   // protect S (ds_reads retired); global stores stay in flight

    // ================= pass 1 (KB, odd output rows) =================
    // KB read inline (coalesced 512B/wave loads, one vmcnt wait).
    #pragma unroll
    for (int it = 0; it < 8; ++it) {
        int j = it*8 + t7;
        float2 kb0 = KpB[it*2048 + kbase];
        float2 kb1 = KpB[it*2048 + kbase + 128];
        float2 vB = (it < 5) ? sB[it] : SB[(it-5)*1024 + tid];
        float2 w0 = cmulf(sA[it], kb0);
        float2 w1 = cmulf(vB, kb1);
        int a = (2*j)*ST2 + nn;
        S[a]       = caddf(w0, w1);
        S[a + ST2] = csubf(w0, w1);
    }
    barrier_lds();

    inv_pair<1,1>(S, TW, tid); barrier_lds();
    inv_pair<1,3>(S, TW, tid); barrier_lds();
    inv_pair<1,5>(S, TW, tid); barrier_lds();
    inv_pair<0,0>(S, TW, tid); barrier_lds();
    inv_pair<0,2>(S, TW, tid); barrier_lds();
    inv_pair<0,4>(S, TW, tid); barrier_lds();

    #pragma unroll
    for (int it = 0; it < 8; ++it) {
        int g = it*1024 + tid;
        int j = g & 63, m = g >> 6;
        int a = m*ST2 + j;
        float2 u = S[a], v = S[a + 64];
        float2 t = cmulcf(v, TW[j]);
        float2 o0 = caddf(u, t);
        float2 o1 = csubf(u, t);
        size_t ro = (size_t)(2*m + 1) * 256;
        *(float2*)(op + ro + 2*j)       = make_float2(o0.x + bv, o0.y + bv);
        *(float2*)(op + ro + 2*j + 128) = make_float2(o1.x + bv, o1.y + bv);
    }
}

extern "C" void kernel_launch(void* const* d_in, const int* in_sizes, int n_in,
                              void* d_out, int out_size, void* d_ws, size_t ws_size,
                              hipStream_t stream)
{
    const float* x      = (const float*)d_in[0];   // [4,64,128,128]
    const float* weight = (const float*)d_in[1];   // [1,64,5,5]
    const float* bias   = (const float*)d_in[2];   // [1,64,1,1]
    const float* lam    = (const float*)d_in[3];   // [1,1,1,1]
    float* out = (float*)d_out;                    // [4,64,256,256]

    float2* KA = (float2*)d_ws;                    // 8 MB
    float2* KB = KA + (size_t)64 * 16384;          // 8 MB

    hipLaunchKernelGGL(precompute_K, dim3(2048), dim3(256), 0, stream,
                       weight, lam, KA, KB);
    hipLaunchKernelGGL(converse_main, dim3(256), dim3(1024), 0, stream,
                       x, bias, KA, KB, out);
}